// Round 2
// baseline (184.228 us; speedup 1.0000x reference)
//
#include <hip/hip_runtime.h>
#include <hip/hip_bf16.h>

#define B 8
#define N 25200
#define ROW 85
#define NC 80
#define K 2048
#define MAXDET 300
#define NBUCKET 16384
#define CAND_CAP 4096
#define NCHUNK 32   /* K/64 */
#define STILE 64    /* score tile rows */

// ---------------------------------------------------------------------------
// Kernel 1: score/cls per box. 64-row tile staged to LDS via coalesced float4
// loads; 4 lanes per box; exact np.argmax first-max tie-break via shuffles.
// ---------------------------------------------------------------------------
__global__ void __launch_bounds__(256)
nms_score_kernel(const float* __restrict__ x,
                 float* __restrict__ scores,
                 int* __restrict__ cls_id) {
    int b = blockIdx.y;
    int i0 = blockIdx.x * STILE;
    int rows = N - i0; if (rows > STILE) rows = STILE;
    __shared__ float lx[STILE * ROW];   // 21760 B
    {
        const float4* s4 = (const float4*)(x + ((size_t)b * N + i0) * ROW);
        float4* d4 = (float4*)lx;
        int nv = rows * ROW / 4;        // 1360 or 1020 (both exact)
        for (int k = threadIdx.x; k < nv; k += 256) d4[k] = s4[k];
    }
    __syncthreads();
    int g = threadIdx.x >> 2;          // box in tile
    int q = threadIdx.x & 3;
    if (g >= rows) return;             // uniform across the 4-lane group
    const float* p = lx + g * ROW;
    float obj = p[4];
    float best = -1e30f;
    int bc = 127;
    if (obj > 0.3f) {
        #pragma unroll
        for (int k = 0; k < 20; ++k) {
            int c = q + 4 * k;
            float v = __fmul_rn(p[5 + c], obj);   // exact, no FMA
            if (v > best) { best = v; bc = c; }   // strict >: in-lane first-max
        }
    }
    #pragma unroll
    for (int m = 1; m < 4; m <<= 1) {   // combine: higher v, tie -> smaller class
        float ov = __shfl_xor(best, m, 64);
        int   oc = __shfl_xor(bc, m, 64);
        if (ov > best || (ov == best && oc < bc)) { best = ov; bc = oc; }
    }
    if (q == 0) {
        int i = i0 + g;
        float score = (obj > 0.3f && best > 0.3f) ? best : -1.0f;
        scores[b * N + i] = score;
        cls_id[b * N + i] = (bc == 127) ? 0 : bc;
    }
}

// ---------------------------------------------------------------------------
// Kernel 2 (fully fused): top-K select (LDS counting sort) + per-class greedy
// NMS + top-300 output, one block per batch, all state LDS-resident.
//   Stage 1 (U.s1 + V.lk): histogram -> descending scan -> placement ->
//           per-bucket insertion sort (identical to previous select kernel).
//   Stage 2 (U.s2, overwrites s1): convert sorted keys to SoA
//           {boxes, shifted, area, score, cls} in LDS.
//   Stage 3 (V.s3, overwrites lk): 16 waves x 5 classes each run the exact
//           per-class greedy scan (cross-class IoU is exactly 0, so the
//           reference's K-long scan decomposes exactly); survivors OR into
//           LDS kept bits.
//   Stage 4: wave 0 emits dets/flags (kept first, then rest, rank order).
// No global intermediates besides scores/cls_id. FP op sequence identical
// to the previously passing kernel (absmax 0.0).
// ---------------------------------------------------------------------------
__global__ void __launch_bounds__(1024, 1)
nms_fused_kernel(const float* __restrict__ scores,
                 const float* __restrict__ x,
                 const int* __restrict__ cls_id,
                 float* __restrict__ out) {
    __shared__ __align__(16) union {
        struct { unsigned loff[NBUCKET]; unsigned lcnt16[NBUCKET / 2]; } s1; // 96 KB
        struct {
            float sx1[K], sy1[K], sx2[K], sy2[K];   // shifted (32 KB)
            float bx1[K], by1[K], bx2[K], by2[K];   // boxes   (32 KB)
            float sar[K];                           // area    (8 KB)
            float ssc[K];                           // score   (8 KB)
            int   scl[K];                           // class   (8 KB)
        } s2;                                       // 88 KB
    } U;
    __shared__ __align__(16) union {
        unsigned long long lk[CAND_CAP];            // 32 KB sort keys
        struct {
            int tmp64[16][64];                      // per-wave compacted ranks
            unsigned long long wmemb[16][NCHUNK];   // general path member bits
            unsigned long long wkeep[16][NCHUNK];   // general path keep bits
            unsigned kept32[2 * NCHUNK];            // global kept bits (u32 atomics)
        } s3;                                       // ~12.3 KB
    } V;
    __shared__ unsigned wsum[16];

    int b = blockIdx.x;
    int t = threadIdx.x;
    int ln = t & 63, wv = t >> 6;
    unsigned long long below = (ln == 0) ? 0ULL : (~0ULL >> (64 - ln));
    constexpr int NITER = (N + 1023) / 1024;    // 25

    {   // zero histogram + cursors + keys
        uint4 z = {0u, 0u, 0u, 0u};
        uint4* d1 = (uint4*)U.s1.loff;
        for (int k = t; k < NBUCKET / 4; k += 1024) d1[k] = z;
        uint4* d2 = (uint4*)U.s1.lcnt16;
        for (int k = t; k < NBUCKET / 8; k += 1024) d2[k] = z;
    }
    for (int k = t; k < CAND_CAP; k += 1024) V.lk[k] = 0ULL;
    __syncthreads();

    // histogram pass: single global read, cache scores in registers
    float sreg[NITER];
    #pragma unroll
    for (int r = 0; r < NITER; ++r) {
        int i = t + r * 1024;
        float s = (i < N) ? scores[b * N + i] : -1.0f;
        sreg[r] = s;
        if (s > 0.0f) {
            int q = (int)(__fmul_rn(s, 16384.0f));
            if (q > NBUCKET - 1) q = NBUCKET - 1;
            atomicAdd(&U.s1.loff[q], 1u);
        }
    }
    __syncthreads();

    // descending exclusive scan: loff[q] = count of elements in buckets > q.
    unsigned v[16];
    int base_j = t * 16;
    unsigned A4 = (unsigned)(NBUCKET - 16 - base_j) / 4;   // ascending uint4 base
    {
        uint4 u0 = ((uint4*)U.s1.loff)[A4 + 0];
        uint4 u1 = ((uint4*)U.s1.loff)[A4 + 1];
        uint4 u2 = ((uint4*)U.s1.loff)[A4 + 2];
        uint4 u3 = ((uint4*)U.s1.loff)[A4 + 3];
        unsigned u[16] = {u0.x,u0.y,u0.z,u0.w, u1.x,u1.y,u1.z,u1.w,
                          u2.x,u2.y,u2.z,u2.w, u3.x,u3.y,u3.z,u3.w};
        #pragma unroll
        for (int k = 0; k < 16; ++k) v[k] = u[15 - k];
    }
    unsigned S = 0;
    #pragma unroll
    for (int k = 0; k < 16; ++k) S += v[k];
    unsigned pref = S;
    #pragma unroll
    for (int o = 1; o < 64; o <<= 1) { unsigned u = __shfl_up(pref, o, 64); if (ln >= o) pref += u; }
    if (ln == 63) wsum[wv] = pref;
    __syncthreads();
    unsigned wbase = 0;
    for (int w = 0; w < wv; ++w) wbase += wsum[w];
    unsigned running = wbase + pref - S;
    {
        unsigned o[16];
        #pragma unroll
        for (int k = 0; k < 16; ++k) { o[15 - k] = running; running += v[k]; }
        ((uint4*)U.s1.loff)[A4 + 0] = make_uint4(o[0],  o[1],  o[2],  o[3]);
        ((uint4*)U.s1.loff)[A4 + 1] = make_uint4(o[4],  o[5],  o[6],  o[7]);
        ((uint4*)U.s1.loff)[A4 + 2] = make_uint4(o[8],  o[9],  o[10], o[11]);
        ((uint4*)U.s1.loff)[A4 + 3] = make_uint4(o[12], o[13], o[14], o[15]);
    }
    __syncthreads();

    // placement (counting sort) from register-cached scores
    #pragma unroll
    for (int r = 0; r < NITER; ++r) {
        float s = sreg[r];
        if (s > 0.0f) {
            int i = t + r * 1024;
            int q = (int)(__fmul_rn(s, 16384.0f));
            if (q > NBUCKET - 1) q = NBUCKET - 1;
            unsigned start = U.s1.loff[q];
            if (start < CAND_CAP) {
                unsigned sh = (q & 1) * 16;
                unsigned old = atomicAdd(&U.s1.lcnt16[q >> 1], 1u << sh);
                unsigned rank = (old >> sh) & 0xFFFFu;
                unsigned pos = start + rank;
                if (pos < CAND_CAP) {
                    unsigned long long key =
                        ((unsigned long long)__float_as_uint(s) << 32) | (unsigned)(~i);
                    V.lk[pos] = key;
                }
            }
        }
    }
    __syncthreads();

    // per-bucket insertion sort (descending keys), disjoint ranges
    for (int q = t; q < NBUCKET; q += 1024) {
        unsigned start = U.s1.loff[q];
        if (start < CAND_CAP) {
            unsigned c = (U.s1.lcnt16[q >> 1] >> ((q & 1) * 16)) & 0xFFFFu;
            unsigned m = c;
            if (m > CAND_CAP - start) m = CAND_CAP - start;
            if (m >= 2) {
                for (unsigned a = start + 1; a < start + m; ++a) {
                    unsigned long long kv = V.lk[a];
                    unsigned p2 = a;
                    while (p2 > start && V.lk[p2 - 1] < kv) { V.lk[p2] = V.lk[p2 - 1]; --p2; }
                    V.lk[p2] = kv;
                }
            }
        }
    }
    __syncthreads();

    // stage 2: convert top-K keys -> SoA in LDS (overwrites s1; lk still live)
    for (int r = t; r < K; r += 1024) {
        unsigned long long key = V.lk[r];
        float s;
        int idx;
        float x1, y1, x2, y2;
        int c;
        if (key == 0ULL) {
            s = -1.0f; x1 = y1 = x2 = y2 = 0.0f; c = 0;
        } else {
            s = __uint_as_float((unsigned)(key >> 32));
            idx = (int)(~(unsigned)key);
            const float* p = x + ((size_t)b * N + idx) * ROW;
            float cx = p[0], cy = p[1], w = p[2], h = p[3];
            float hx = __fmul_rn(w, 0.5f);
            float hy = __fmul_rn(h, 0.5f);
            x1 = __fsub_rn(cx, hx); y1 = __fsub_rn(cy, hy);
            x2 = __fadd_rn(cx, hx); y2 = __fadd_rn(cy, hy);
            c = cls_id[b * N + idx];
        }
        U.s2.ssc[r] = s;
        U.s2.bx1[r] = x1; U.s2.by1[r] = y1;
        U.s2.bx2[r] = x2; U.s2.by2[r] = y2;
        U.s2.scl[r] = c;
        float sh = __fmul_rn((float)c, 4096.0f);
        float sx1 = __fadd_rn(x1, sh), sy1 = __fadd_rn(y1, sh);
        float sx2 = __fadd_rn(x2, sh), sy2 = __fadd_rn(y2, sh);
        U.s2.sx1[r] = sx1; U.s2.sy1[r] = sy1;
        U.s2.sx2[r] = sx2; U.s2.sy2[r] = sy2;
        U.s2.sar[r] = __fmul_rn(__fsub_rn(sx2, sx1), __fsub_rn(sy2, sy1));
    }
    __syncthreads();            // lk dead from here; V.s3 becomes valid scratch
    if (t < 2 * NCHUNK) V.s3.kept32[t] = 0u;
    __syncthreads();

    // stage 3: per-class greedy NMS, 16 waves x 5 classes each
    for (int c = wv; c < NC; c += 16) {
        // ordered compaction of this class's ranks (rank-ascending)
        int n = 0;
        for (int ch = 0; ch < NCHUNK; ++ch) {
            int r = ch * 64 + ln;
            bool sel = (U.s2.scl[r] == c) && (U.s2.ssc[r] > 0.0f);
            unsigned long long m = __ballot(sel);
            int pos = n + __popcll(m & below);
            if (sel && pos < 64) V.s3.tmp64[wv][pos] = r;
            n += __popcll(m);
        }
        if (n == 0) continue;

        if (n <= 64) {
            // fast path: member ln lives in lane ln's registers
            int r = -1;
            float x1 = 0.f, y1 = 0.f, x2 = 0.f, y2 = 0.f, ar = 0.f;
            if (ln < n) {
                r = V.s3.tmp64[wv][ln];
                x1 = U.s2.sx1[r]; y1 = U.s2.sy1[r];
                x2 = U.s2.sx2[r]; y2 = U.s2.sy2[r];
                ar = U.s2.sar[r];
            }
            unsigned long long keepw = (n == 64) ? ~0ULL : ((1ULL << n) - 1ULL);
            for (int i = 0; i < n; ++i) {
                if (!((keepw >> i) & 1ULL)) continue;   // uniform
                float bx1 = __shfl(x1, i, 64), by1 = __shfl(y1, i, 64);
                float bx2 = __shfl(x2, i, 64), by2 = __shfl(y2, i, 64);
                float ba  = __shfl(ar, i, 64);
                bool cond = false;
                if (ln > i && ln < n) {
                    float lx = fmaxf(bx1, x1), ly = fmaxf(by1, y1);
                    float rx = fminf(bx2, x2), ry = fminf(by2, y2);
                    float w = fmaxf(__fsub_rn(rx, lx), 0.0f);
                    float h = fmaxf(__fsub_rn(ry, ly), 0.0f);
                    float inter = __fmul_rn(w, h);
                    float denom = __fadd_rn(__fsub_rn(__fadd_rn(ba, ar), inter), 1e-9f);
                    cond = __fdiv_rn(inter, denom) > 0.6f;   // exact ref order
                }
                keepw &= ~__ballot(cond);
            }
            if (ln < n && ((keepw >> ln) & 1ULL))
                atomicOr(&V.s3.kept32[r >> 5], 1u << (r & 31));
        } else {
            // general path (n > 64): per-wave bitmask greedy; correctness-only.
            unsigned long long* memb = V.s3.wmemb[wv];
            unsigned long long* keep = V.s3.wkeep[wv];
            for (int ch = 0; ch < NCHUNK; ++ch) {
                int r = ch * 64 + ln;
                bool sel = (U.s2.scl[r] == c) && (U.s2.ssc[r] > 0.0f);
                unsigned long long m = __ballot(sel);
                if (ln == 0) { memb[ch] = m; keep[ch] = m; }
            }
            for (int i = 0; i < K; ++i) {
                unsigned long long bi = 1ULL << (i & 63);
                if (!(memb[i >> 6] & keep[i >> 6] & bi)) continue;   // uniform
                float bx1 = U.s2.sx1[i], by1 = U.s2.sy1[i];
                float bx2 = U.s2.sx2[i], by2 = U.s2.sy2[i];
                float ba  = U.s2.sar[i];
                for (int ch = i >> 6; ch < NCHUNK; ++ch) {
                    int r = ch * 64 + ln;
                    bool cond = false;
                    if (r > i && ((memb[ch] >> ln) & 1ULL)) {
                        float lx = fmaxf(bx1, U.s2.sx1[r]);
                        float ly = fmaxf(by1, U.s2.sy1[r]);
                        float rx = fminf(bx2, U.s2.sx2[r]);
                        float ry = fminf(by2, U.s2.sy2[r]);
                        float w = fmaxf(__fsub_rn(rx, lx), 0.0f);
                        float h = fmaxf(__fsub_rn(ry, ly), 0.0f);
                        float inter = __fmul_rn(w, h);
                        float denom = __fadd_rn(__fsub_rn(__fadd_rn(ba, U.s2.sar[r]), inter), 1e-9f);
                        cond = __fdiv_rn(inter, denom) > 0.6f;
                    }
                    unsigned long long sup = __ballot(cond);
                    if (ln == 0) keep[ch] &= ~sup;
                }
            }
            for (int ch = 0; ch < NCHUNK; ++ch) {
                int r = ch * 64 + ln;
                if ((keep[ch] >> ln) & 1ULL)
                    atomicOr(&V.s3.kept32[r >> 5], 1u << (r & 31));
            }
        }
    }
    __syncthreads();

    // stage 4: output (wave 0): kept first in rank order, then rest; top-300
    if (wv == 0) {
        int total = 0;
        for (int c = 0; c < NCHUNK; ++c) {
            unsigned long long m = (unsigned long long)V.s3.kept32[2 * c]
                                 | ((unsigned long long)V.s3.kept32[2 * c + 1] << 32);
            total += __popcll(m);
        }
        float* dets  = out + (size_t)b * MAXDET * 6;
        float* flags = out + (size_t)B * MAXDET * 6 + (size_t)b * MAXDET;
        int kc = 0, nc2 = 0;
        for (int c = 0; c < NCHUNK; ++c) {
            int i = c * 64 + ln;
            unsigned long long m = (unsigned long long)V.s3.kept32[2 * c]
                                 | ((unsigned long long)V.s3.kept32[2 * c + 1] << 32);
            bool k = ((m >> ln) & 1ULL) != 0ULL;
            int pc = __popcll(m);
            int slot = k ? (kc + __popcll(m & below))
                         : (total + nc2 + __popcll((~m) & below));
            if (slot < MAXDET) {
                dets[slot * 6 + 0] = U.s2.bx1[i];
                dets[slot * 6 + 1] = U.s2.by1[i];
                dets[slot * 6 + 2] = U.s2.bx2[i];
                dets[slot * 6 + 3] = U.s2.by2[i];
                dets[slot * 6 + 4] = U.s2.ssc[i];
                dets[slot * 6 + 5] = (float)U.s2.scl[i];
                flags[slot] = k ? 1.0f : 0.0f;
            }
            kc += pc;
            nc2 += 64 - pc;
        }
    }
}

// ---------------------------------------------------------------------------
extern "C" void kernel_launch(void* const* d_in, const int* in_sizes, int n_in,
                              void* d_out, int out_size, void* d_ws, size_t ws_size,
                              hipStream_t stream) {
    const float* x = (const float*)d_in[0];
    float* out = (float*)d_out;

    char* ws = (char*)d_ws;
    size_t off = 0;
    auto alloc = [&](size_t bytes) -> void* {
        void* p = ws + off;
        off += bytes;
        off = (off + 255) & ~(size_t)255;
        return p;
    };

    float* scores = (float*) alloc((size_t)B * N * 4);
    int*   cls_id = (int*)   alloc((size_t)B * N * 4);
    (void)ws_size; // needs ~1.7 MB

    nms_score_kernel<<<dim3((N + STILE - 1) / STILE, B), 256, 0, stream>>>(x, scores, cls_id);
    nms_fused_kernel<<<B, 1024, 0, stream>>>(scores, x, cls_id, out);
}

// Round 3
// 144.488 us; speedup vs baseline: 1.2750x; 1.2750x over previous
//
#include <hip/hip_runtime.h>
#include <hip/hip_bf16.h>

#define B 8
#define N 25200
#define ROW 85
#define NC 80
#define K 2048
#define MAXDET 300
#define NBUCKET 16384
#define CAND_CAP 4096
#define NCHUNK 32   /* K/64 */
#define STILE 64    /* score tile rows */

// ---------------------------------------------------------------------------
// Kernel 1: score/cls per box + global per-batch 16K-bin score histogram.
// Score is in-register at emit time, so the histogram costs ~45 scattered
// global atomicAdds per 64-box block (spread over 128K addresses).
// ---------------------------------------------------------------------------
__global__ void __launch_bounds__(256)
nms_score_kernel(const float* __restrict__ x,
                 float* __restrict__ scores,
                 int* __restrict__ cls_id,
                 unsigned* __restrict__ hist) {
    int b = blockIdx.y;
    int i0 = blockIdx.x * STILE;
    int rows = N - i0; if (rows > STILE) rows = STILE;
    __shared__ float lx[STILE * ROW];   // 21760 B
    {
        const float4* s4 = (const float4*)(x + ((size_t)b * N + i0) * ROW);
        float4* d4 = (float4*)lx;
        int nv = rows * ROW / 4;        // 1360 or 1020 (both exact)
        for (int k = threadIdx.x; k < nv; k += 256) d4[k] = s4[k];
    }
    __syncthreads();
    int g = threadIdx.x >> 2;          // box in tile
    int q = threadIdx.x & 3;
    if (g >= rows) return;             // uniform across the 4-lane group
    const float* p = lx + g * ROW;
    float obj = p[4];
    float best = -1e30f;
    int bc = 127;
    if (obj > 0.3f) {
        #pragma unroll
        for (int k = 0; k < 20; ++k) {
            int c = q + 4 * k;
            float v = __fmul_rn(p[5 + c], obj);   // exact, no FMA
            if (v > best) { best = v; bc = c; }   // strict >: in-lane first-max
        }
    }
    #pragma unroll
    for (int m = 1; m < 4; m <<= 1) {   // combine: higher v, tie -> smaller class
        float ov = __shfl_xor(best, m, 64);
        int   oc = __shfl_xor(bc, m, 64);
        if (ov > best || (ov == best && oc < bc)) { best = ov; bc = oc; }
    }
    if (q == 0) {
        int i = i0 + g;
        float score = (obj > 0.3f && best > 0.3f) ? best : -1.0f;
        scores[b * N + i] = score;
        cls_id[b * N + i] = (bc == 127) ? 0 : bc;
        if (score > 0.0f) {
            int qb = (int)(__fmul_rn(score, 16384.0f));   // identical to select's mapping
            if (qb > NBUCKET - 1) qb = NBUCKET - 1;
            atomicAdd(&hist[b * NBUCKET + qb], 1u);
        }
    }
}

// ---------------------------------------------------------------------------
// Kernel 2 (select): reads the prebuilt histogram (64 KB coalesced) ->
// descending exclusive scan -> counting-sort placement (single N-pass over
// scores) -> per-bucket insertion sort (canonicalizes order via full
// (score,~idx) keys) -> gather top-K boxes/cls/shifted/area.
// 128 KB LDS -> 1 block/CU. Also zeroes this batch's keepbits.
// ---------------------------------------------------------------------------
__global__ void __launch_bounds__(1024, 1)
nms_select_kernel(const float* __restrict__ scores,
                  const float* __restrict__ x,
                  const int* __restrict__ cls_id,
                  const unsigned* __restrict__ hist,
                  float* __restrict__ top_s,
                  float* __restrict__ boxes,
                  int* __restrict__ clsk,
                  float* __restrict__ shifted,
                  float* __restrict__ area,
                  unsigned long long* __restrict__ keepbits) {
    __shared__ unsigned loff[NBUCKET];          // start ranks (scan output)
    __shared__ unsigned lcnt16[NBUCKET / 2];    // packed u16 cursors
    __shared__ unsigned long long lk[CAND_CAP]; // packed sort keys
    __shared__ unsigned wsum[16];

    int b = blockIdx.x;
    int t = threadIdx.x;
    int ln = t & 63, wv = t >> 6;
    constexpr int NITER = (N + 1023) / 1024;    // 25

    if (t < NCHUNK) keepbits[b * NCHUNK + t] = 0ULL;

    {   // zero cursors + keys (loff is fully overwritten by the scan)
        uint4 z = {0u, 0u, 0u, 0u};
        uint4* d2 = (uint4*)lcnt16;
        for (int k = t; k < NBUCKET / 8; k += 1024) d2[k] = z;
    }
    for (int k = t; k < CAND_CAP; k += 1024) lk[k] = 0ULL;

    // descending exclusive scan of the global histogram:
    // loff[q] = count of elements in buckets > q.
    // thread t owns buckets NBUCKET-1-16t .. NBUCKET-16-16t.
    unsigned v[16];
    int base_j = t * 16;
    unsigned A4 = (unsigned)(NBUCKET - 16 - base_j) / 4;   // ascending uint4 base
    {
        const uint4* gh = (const uint4*)(hist + (size_t)b * NBUCKET);
        uint4 u0 = gh[A4 + 0];
        uint4 u1 = gh[A4 + 1];
        uint4 u2 = gh[A4 + 2];
        uint4 u3 = gh[A4 + 3];
        unsigned u[16] = {u0.x,u0.y,u0.z,u0.w, u1.x,u1.y,u1.z,u1.w,
                          u2.x,u2.y,u2.z,u2.w, u3.x,u3.y,u3.z,u3.w};
        #pragma unroll
        for (int k = 0; k < 16; ++k) v[k] = u[15 - k];
    }
    unsigned S = 0;
    #pragma unroll
    for (int k = 0; k < 16; ++k) S += v[k];
    unsigned pref = S;
    #pragma unroll
    for (int o = 1; o < 64; o <<= 1) { unsigned u = __shfl_up(pref, o, 64); if (ln >= o) pref += u; }
    if (ln == 63) wsum[wv] = pref;
    __syncthreads();            // also covers lcnt16/lk zeroing
    unsigned wbase = 0;
    for (int w = 0; w < wv; ++w) wbase += wsum[w];
    unsigned running = wbase + pref - S;
    {
        unsigned o[16];
        #pragma unroll
        for (int k = 0; k < 16; ++k) { o[15 - k] = running; running += v[k]; }
        ((uint4*)loff)[A4 + 0] = make_uint4(o[0],  o[1],  o[2],  o[3]);
        ((uint4*)loff)[A4 + 1] = make_uint4(o[4],  o[5],  o[6],  o[7]);
        ((uint4*)loff)[A4 + 2] = make_uint4(o[8],  o[9],  o[10], o[11]);
        ((uint4*)loff)[A4 + 3] = make_uint4(o[12], o[13], o[14], o[15]);
    }
    __syncthreads();

    // placement (counting sort): the single N-scaled pass over scores
    float sreg[NITER];
    #pragma unroll
    for (int r = 0; r < NITER; ++r) {
        int i = t + r * 1024;
        sreg[r] = (i < N) ? scores[b * N + i] : -1.0f;
    }
    #pragma unroll
    for (int r = 0; r < NITER; ++r) {
        float s = sreg[r];
        if (s > 0.0f) {
            int i = t + r * 1024;
            int q = (int)(__fmul_rn(s, 16384.0f));
            if (q > NBUCKET - 1) q = NBUCKET - 1;
            unsigned start = loff[q];
            if (start < CAND_CAP) {
                unsigned sh = (q & 1) * 16;
                unsigned old = atomicAdd(&lcnt16[q >> 1], 1u << sh);
                unsigned rank = (old >> sh) & 0xFFFFu;
                unsigned pos = start + rank;
                if (pos < CAND_CAP) {
                    unsigned long long key =
                        ((unsigned long long)__float_as_uint(s) << 32) | (unsigned)(~i);
                    lk[pos] = key;
                }
            }
        }
    }
    __syncthreads();

    // per-bucket insertion sort (descending keys), disjoint ranges
    for (int q = t; q < NBUCKET; q += 1024) {
        unsigned start = loff[q];
        if (start < CAND_CAP) {
            unsigned c = (lcnt16[q >> 1] >> ((q & 1) * 16)) & 0xFFFFu;
            unsigned m = c;
            if (m > CAND_CAP - start) m = CAND_CAP - start;
            if (m >= 2) {
                for (unsigned a = start + 1; a < start + m; ++a) {
                    unsigned long long kv = lk[a];
                    unsigned p2 = a;
                    while (p2 > start && lk[p2 - 1] < kv) { lk[p2] = lk[p2 - 1]; --p2; }
                    lk[p2] = kv;
                }
            }
        }
    }
    __syncthreads();

    // gather top-K
    for (int r = t; r < K; r += 1024) {
        unsigned long long key = lk[r];
        float s;
        int idx;
        float x1, y1, x2, y2;
        int c;
        if (key == 0ULL) {
            s = -1.0f; x1 = y1 = x2 = y2 = 0.0f; c = 0;
        } else {
            s = __uint_as_float((unsigned)(key >> 32));
            idx = (int)(~(unsigned)key);
            const float* p = x + ((size_t)b * N + idx) * ROW;
            float cx = p[0], cy = p[1], w = p[2], h = p[3];
            float hx = __fmul_rn(w, 0.5f);
            float hy = __fmul_rn(h, 0.5f);
            x1 = __fsub_rn(cx, hx); y1 = __fsub_rn(cy, hy);
            x2 = __fadd_rn(cx, hx); y2 = __fadd_rn(cy, hy);
            c = cls_id[b * N + idx];
        }
        int o = b * K + r;
        top_s[o] = s;
        boxes[o * 4 + 0] = x1; boxes[o * 4 + 1] = y1;
        boxes[o * 4 + 2] = x2; boxes[o * 4 + 3] = y2;
        clsk[o] = c;
        float sh = __fmul_rn((float)c, 4096.0f);
        float sx1 = __fadd_rn(x1, sh), sy1 = __fadd_rn(y1, sh);
        float sx2 = __fadd_rn(x2, sh), sy2 = __fadd_rn(y2, sh);
        shifted[o * 4 + 0] = sx1; shifted[o * 4 + 1] = sy1;
        shifted[o * 4 + 2] = sx2; shifted[o * 4 + 3] = sy2;
        area[o] = __fmul_rn(__fsub_rn(sx2, sx1), __fsub_rn(sy2, sy1));
    }
}

// ---------------------------------------------------------------------------
// Kernel 3: per-class greedy NMS (640 parallel waves). Cross-class IoU is
// exactly 0 (class shift 4096 >> max coord 720), so the reference's K-long
// sequential scan decomposes exactly into 80 independent per-class scans.
// ---------------------------------------------------------------------------
__global__ void __launch_bounds__(64)
nms_class_kernel(const float* __restrict__ top_s,
                 const int* __restrict__ clsk,
                 const float* __restrict__ shifted,
                 const float* __restrict__ area,
                 unsigned long long* __restrict__ keepbits) {
    int c = blockIdx.x, b = blockIdx.y;
    int t = threadIdx.x;   // 0..63
    unsigned long long below = (t == 0) ? 0ULL : (~0ULL >> (64 - t));

    __shared__ int srank[K];                    // 8 KB
    __shared__ unsigned long long skeep[NCHUNK];

    // ordered compaction: ranks of this class with valid score, rank-ascending
    int n = 0;
    for (int ch = 0; ch < NCHUNK; ++ch) {
        int r = ch * 64 + t;
        bool sel = (clsk[b * K + r] == c) && (top_s[b * K + r] > 0.0f);
        unsigned long long m = __ballot(sel);
        if (sel) srank[n + __popcll(m & below)] = r;
        n += __popcll(m);
    }
    __syncthreads();
    if (n == 0) return;

    if (n <= 64) {
        // fast path: member t lives in lane t's registers
        float x1 = 0.f, y1 = 0.f, x2 = 0.f, y2 = 0.f, ar = 0.f;
        int r = -1;
        if (t < n) {
            r = srank[t];
            const float* sb = shifted + ((size_t)b * K + r) * 4;
            x1 = sb[0]; y1 = sb[1]; x2 = sb[2]; y2 = sb[3];
            ar = area[b * K + r];
        }
        unsigned long long keepw = (n == 64) ? ~0ULL : ((1ULL << n) - 1ULL);
        for (int i = 0; i < n; ++i) {
            if (!((keepw >> i) & 1ULL)) continue;   // uniform
            float bx1 = __shfl(x1, i, 64), by1 = __shfl(y1, i, 64);
            float bx2 = __shfl(x2, i, 64), by2 = __shfl(y2, i, 64);
            float ba  = __shfl(ar, i, 64);
            bool cond = false;
            if (t > i && t < n) {
                float lx = fmaxf(bx1, x1), ly = fmaxf(by1, y1);
                float rx = fminf(bx2, x2), ry = fminf(by2, y2);
                float w = fmaxf(__fsub_rn(rx, lx), 0.0f);
                float h = fmaxf(__fsub_rn(ry, ly), 0.0f);
                float inter = __fmul_rn(w, h);
                float denom = __fadd_rn(__fsub_rn(__fadd_rn(ba, ar), inter), 1e-9f);
                cond = __fdiv_rn(inter, denom) > 0.6f;   // exact ref order
            }
            keepw &= ~__ballot(cond);
        }
        if (t < n && ((keepw >> t) & 1ULL))
            atomicOr(&keepbits[b * NCHUNK + (r >> 6)], 1ULL << (r & 63));
        return;
    }

    // general path (n > 64): LDS keep bits, boxes re-read from global.
    // Correctness-only; unreachable for this data distribution.
    for (int w = t; w < NCHUNK; w += 64) {
        int lo = w * 64;
        unsigned long long vw;
        if (n >= lo + 64)      vw = ~0ULL;
        else if (n <= lo)      vw = 0ULL;
        else                   vw = (1ULL << (n - lo)) - 1ULL;
        skeep[w] = vw;
    }
    __syncthreads();
    for (int i = 0; i < n; ++i) {
        if (!((skeep[i >> 6] >> (i & 63)) & 1ULL)) continue;   // uniform
        int ri = srank[i];
        const float* sbi = shifted + ((size_t)b * K + ri) * 4;
        float bx1 = sbi[0], by1 = sbi[1], bx2 = sbi[2], by2 = sbi[3];
        float ba = area[b * K + ri];
        int jb_hi = (n - 1) >> 6;
        for (int jb2 = (i + 1) >> 6; jb2 <= jb_hi; ++jb2) {
            int j = jb2 * 64 + t;
            bool cond = false;
            if (j > i && j < n) {
                int rj = srank[j];
                const float* sbj = shifted + ((size_t)b * K + rj) * 4;
                float x1 = sbj[0], y1 = sbj[1], x2 = sbj[2], y2 = sbj[3];
                float arj = area[b * K + rj];
                float lx = fmaxf(bx1, x1), ly = fmaxf(by1, y1);
                float rx = fminf(bx2, x2), ry = fminf(by2, y2);
                float w = fmaxf(__fsub_rn(rx, lx), 0.0f);
                float h = fmaxf(__fsub_rn(ry, ly), 0.0f);
                float inter = __fmul_rn(w, h);
                float denom = __fadd_rn(__fsub_rn(__fadd_rn(ba, arj), inter), 1e-9f);
                cond = __fdiv_rn(inter, denom) > 0.6f;
            }
            unsigned long long sup = __ballot(cond);
            if (t == 0) skeep[jb2] &= ~sup;
        }
        __syncthreads();
    }
    for (int j = t; j < n; j += 64) {
        if ((skeep[j >> 6] >> (j & 63)) & 1ULL) {
            int r = srank[j];
            atomicOr(&keepbits[b * NCHUNK + (r >> 6)], 1ULL << (r & 63));
        }
    }
}

// ---------------------------------------------------------------------------
// Kernel 4: output phase. Kept boxes first in rank order, then non-kept in
// rank order; top-300 slots.
// ---------------------------------------------------------------------------
__global__ void __launch_bounds__(64)
nms_out_kernel(const unsigned long long* __restrict__ keepbits,
               const float* __restrict__ top_s,
               const float* __restrict__ boxes,
               const int* __restrict__ clsk,
               float* __restrict__ out) {
    int b = blockIdx.x;
    int lane = threadIdx.x;
    __shared__ unsigned long long kept[NCHUNK];
    if (lane < NCHUNK) kept[lane] = keepbits[b * NCHUNK + lane];
    __syncthreads();

    int total = 0;
    for (int c = 0; c < NCHUNK; ++c) total += __popcll(kept[c]);

    float* dets  = out + (size_t)b * MAXDET * 6;
    float* flags = out + (size_t)B * MAXDET * 6 + (size_t)b * MAXDET;
    unsigned long long below = (lane == 0) ? 0ULL : (~0ULL >> (64 - lane));
    int kc = 0, nc2 = 0;
    for (int c = 0; c < NCHUNK; ++c) {
        int i = c * 64 + lane;
        unsigned long long m = kept[c];
        bool k = ((m >> lane) & 1ULL) != 0ULL;
        int pc = __popcll(m);
        int slot = k ? (kc + __popcll(m & below))
                     : (total + nc2 + __popcll((~m) & below));
        if (slot < MAXDET) {
            int o = b * K + i;
            dets[slot * 6 + 0] = boxes[o * 4 + 0];
            dets[slot * 6 + 1] = boxes[o * 4 + 1];
            dets[slot * 6 + 2] = boxes[o * 4 + 2];
            dets[slot * 6 + 3] = boxes[o * 4 + 3];
            dets[slot * 6 + 4] = top_s[o];
            dets[slot * 6 + 5] = (float)clsk[o];
            flags[slot] = k ? 1.0f : 0.0f;
        }
        kc += pc;
        nc2 += 64 - pc;
    }
}

// ---------------------------------------------------------------------------
extern "C" void kernel_launch(void* const* d_in, const int* in_sizes, int n_in,
                              void* d_out, int out_size, void* d_ws, size_t ws_size,
                              hipStream_t stream) {
    const float* x = (const float*)d_in[0];
    float* out = (float*)d_out;

    char* ws = (char*)d_ws;
    size_t off = 0;
    auto alloc = [&](size_t bytes) -> void* {
        void* p = ws + off;
        off += bytes;
        off = (off + 255) & ~(size_t)255;
        return p;
    };

    float*    scores = (float*)    alloc((size_t)B * N * 4);
    int*      cls_id = (int*)      alloc((size_t)B * N * 4);
    float*    top_s  = (float*)    alloc((size_t)B * K * 4);
    float*    boxes  = (float*)    alloc((size_t)B * K * 4 * 4);
    int*      clsk   = (int*)      alloc((size_t)B * K * 4);
    float*    shifted= (float*)    alloc((size_t)B * K * 4 * 4);
    float*    area   = (float*)    alloc((size_t)B * K * 4);
    unsigned long long* keepbits = (unsigned long long*) alloc((size_t)B * NCHUNK * 8);
    unsigned* hist   = (unsigned*) alloc((size_t)B * NBUCKET * 4);
    (void)ws_size; // needs ~2.8 MB

    hipMemsetAsync(hist, 0, (size_t)B * NBUCKET * 4, stream);
    nms_score_kernel<<<dim3((N + STILE - 1) / STILE, B), 256, 0, stream>>>(x, scores, cls_id, hist);
    nms_select_kernel<<<B, 1024, 0, stream>>>(scores, x, cls_id, hist,
                                              top_s, boxes, clsk, shifted, area, keepbits);
    nms_class_kernel<<<dim3(NC, B), 64, 0, stream>>>(top_s, clsk, shifted, area, keepbits);
    nms_out_kernel<<<B, 64, 0, stream>>>(keepbits, top_s, boxes, clsk, out);
}